// Round 4
// baseline (564.552 us; speedup 1.0000x reference)
//
#include <hip/hip_runtime.h>
#include <hip/hip_bf16.h>
#include <math.h>

#define N_NODES 100000
#define N_EDGES 800000
#define H 256
#define NTYPES 22
#define SCAN_G 98                       // ceil(100000/1024)
#define GRID_G ((N_NODES + 63) / 64)    // 1563 blocks of BM=64

typedef __attribute__((ext_vector_type(8))) short short8;
typedef __attribute__((ext_vector_type(4))) float f32x4;
typedef unsigned short u16;

__device__ __forceinline__ u16 f2bf(float f) {
    unsigned u = __float_as_uint(f);
    u += 0x7FFF + ((u >> 16) & 1);      // RNE
    return (u16)(u >> 16);
}
__device__ __forceinline__ float bf2f(u16 u) {
    return __uint_as_float(((unsigned)u) << 16);
}

// async global->LDS, 16B per lane; LDS dest must be wave-uniform base + lane*16
__device__ __forceinline__ void gload16(const void* g, void* l) {
    __builtin_amdgcn_global_load_lds(
        (const __attribute__((address_space(1))) unsigned int*)g,
        (__attribute__((address_space(3))) unsigned int*)l, 16, 0, 0);
}

// ---------------------------------------------------------------------------
// prep_small: C1 = temp_W @ W1b (32x256), C2 = emb @ W1c (22x256),
// beff = fus_b1 + temp_b @ W1b (256)
// ---------------------------------------------------------------------------
__global__ __launch_bounds__(256) void prep_small(
    const float* __restrict__ temp_W, const float* __restrict__ temp_b,
    const float* __restrict__ emb, const float* __restrict__ fus_W1,
    const float* __restrict__ fus_b1,
    float* __restrict__ C1, float* __restrict__ C2, float* __restrict__ beff)
{
    int b = blockIdx.x;
    int j = threadIdx.x;
    if (b < 32) {
        float acc = 0.f;
        #pragma unroll 8
        for (int m = 0; m < H; ++m)
            acc += temp_W[b * H + m] * fus_W1[(size_t)(H + m) * H + j];
        C1[b * H + j] = acc;
    } else if (b < 32 + NTYPES) {
        int e = b - 32;
        float acc = 0.f;
        #pragma unroll 8
        for (int m = 0; m < H; ++m)
            acc += emb[e * H + m] * fus_W1[(size_t)(2 * H + m) * H + j];
        C2[e * H + j] = acc;
    } else {
        float acc = fus_b1[j];
        #pragma unroll 8
        for (int m = 0; m < H; ++m)
            acc += temp_b[m] * fus_W1[(size_t)(H + m) * H + j];
        beff[j] = acc;
    }
}

// ---------------------------------------------------------------------------
// prep_frag: pack weights into MFMA B-fragment order, bf16.
// Blob: kstep s (49) x chunk c (1024) x 8 bf16.  c: ntile=c>>6, l=c&63 ->
// col n = ntile*16+(l&15), k_in_step = 8*(l>>4)+i.
// s 0..7: fus_W1 clause part, s=8: C1, s 9..16: fus_W2,
// s 17..32: deriv_W[0], s 33..48: deriv_W[1].
// ---------------------------------------------------------------------------
__global__ __launch_bounds__(256) void prep_frag(
    const float* __restrict__ fus_W1, const float* __restrict__ C1,
    const float* __restrict__ fus_W2, const float* __restrict__ deriv_W,
    u16* __restrict__ wblob)
{
    int s = blockIdx.x;
    const float* src; int kbase;
    if (s < 8)       { src = fus_W1;              kbase = s * 32; }
    else if (s == 8) { src = C1;                  kbase = 0; }
    else if (s < 17) { src = fus_W2;              kbase = (s - 9) * 32; }
    else if (s < 33) { src = deriv_W;             kbase = (s - 17) * 32; }
    else             { src = deriv_W + 512 * H;   kbase = (s - 33) * 32; }
    #pragma unroll
    for (int it = 0; it < 4; ++it) {
        int c = it * 256 + threadIdx.x;
        int l = c & 63, nt = c >> 6;
        int n = (nt << 4) | (l & 15);
        int k0 = kbase + ((l >> 4) << 3);
        short8 v;
        #pragma unroll
        for (int i = 0; i < 8; ++i)
            v[i] = (short)f2bf(src[(size_t)(k0 + i) * H + n]);
        *reinterpret_cast<short8*>(wblob + (size_t)s * 8192 + (size_t)c * 8) = v;
    }
}

// ---------------------------------------------------------------------------
// CSR build
// ---------------------------------------------------------------------------
__global__ void count_kernel(const int* __restrict__ dst, int* __restrict__ cnt)
{
    int e = blockIdx.x * blockDim.x + threadIdx.x;
    if (e < N_EDGES) atomicAdd(&cnt[dst[e]], 1);
}

__global__ __launch_bounds__(1024) void scan1_kernel(
    const int* __restrict__ cnt, int* __restrict__ off, int* __restrict__ bsum)
{
    __shared__ int s[1024];
    int i = blockIdx.x * 1024 + threadIdx.x;
    int v = (i < N_NODES) ? cnt[i] : 0;
    s[threadIdx.x] = v;
    __syncthreads();
    #pragma unroll
    for (int o = 1; o < 1024; o <<= 1) {
        int t = (threadIdx.x >= o) ? s[threadIdx.x - o] : 0;
        __syncthreads();
        s[threadIdx.x] += t;
        __syncthreads();
    }
    if (i < N_NODES) off[i] = s[threadIdx.x];
    if (threadIdx.x == 1023) bsum[blockIdx.x] = s[1023];
}

__global__ void scan2_kernel(const int* __restrict__ bsum, int* __restrict__ bbase)
{
    if (threadIdx.x == 0) {
        int acc = 0;
        for (int b = 0; b < SCAN_G; ++b) { bbase[b] = acc; acc += bsum[b]; }
    }
}

__global__ __launch_bounds__(1024) void scan3_kernel(
    int* __restrict__ off, const int* __restrict__ bbase,
    const int* __restrict__ cnt, int* __restrict__ cursor)
{
    int i = blockIdx.x * 1024 + threadIdx.x;
    if (i < N_NODES) {
        int incl = off[i] + bbase[blockIdx.x];
        off[i] = incl;
        cursor[i] = incl - cnt[i];
    }
}

__global__ void fill_kernel(const int* __restrict__ src, const int* __restrict__ dst,
                            int* __restrict__ cursor, int* __restrict__ csr)
{
    int e = blockIdx.x * blockDim.x + threadIdx.x;
    if (e < N_EDGES) {
        int pos = atomicAdd(&cursor[dst[e]], 1);
        csr[pos] = src[e];
    }
}

// ---------------------------------------------------------------------------
// gather_kernel: one wave per node; mean of parent rows (bf16 in/out)
// ---------------------------------------------------------------------------
__global__ __launch_bounds__(256) void gather_kernel(
    const u16* __restrict__ xb, const int* __restrict__ csr,
    const int* __restrict__ off, const int* __restrict__ cnt,
    u16* __restrict__ agg)
{
    int node = blockIdx.x * 4 + (threadIdx.x >> 6);
    int l = threadIdx.x & 63;
    int deg = cnt[node];
    int start = off[node] - deg;
    float a0 = 0.f, a1 = 0.f, a2 = 0.f, a3 = 0.f;
    float b0 = 0.f, b1 = 0.f, b2 = 0.f, b3 = 0.f;
    int j = 0;
    for (; j + 1 < deg; j += 2) {
        int s0 = csr[start + j], s1 = csr[start + j + 1];
        ushort4 v0 = *reinterpret_cast<const ushort4*>(xb + (size_t)s0 * H + l * 4);
        ushort4 v1 = *reinterpret_cast<const ushort4*>(xb + (size_t)s1 * H + l * 4);
        a0 += bf2f(v0.x); a1 += bf2f(v0.y); a2 += bf2f(v0.z); a3 += bf2f(v0.w);
        b0 += bf2f(v1.x); b1 += bf2f(v1.y); b2 += bf2f(v1.z); b3 += bf2f(v1.w);
    }
    if (j < deg) {
        int s0 = csr[start + j];
        ushort4 v0 = *reinterpret_cast<const ushort4*>(xb + (size_t)s0 * H + l * 4);
        a0 += bf2f(v0.x); a1 += bf2f(v0.y); a2 += bf2f(v0.z); a3 += bf2f(v0.w);
    }
    float sc = 1.0f / fmaxf((float)deg, 1.0f);
    ushort4 o;
    o.x = f2bf((a0 + b0) * sc); o.y = f2bf((a1 + b1) * sc);
    o.z = f2bf((a2 + b2) * sc); o.w = f2bf((a3 + b3) * sc);
    *reinterpret_cast<ushort4*>(agg + (size_t)node * H + l * 4) = o;
}

// ---------------------------------------------------------------------------
// MFMA core: one 32-k step.  Af: 64 lanes*8 u16 per m-tile row-frag;
// Bf: per (w,n) tile 64 lanes*8 u16.
// ---------------------------------------------------------------------------
__device__ __forceinline__ void mfma_step(const u16* Af, const u16* Bf,
                                          int w, int l, f32x4 acc[4][4])
{
    short8 a[4];
    #pragma unroll
    for (int m = 0; m < 4; ++m)
        a[m] = *reinterpret_cast<const short8*>(Af + (size_t)((m << 6) | l) * 8);
    #pragma unroll
    for (int n = 0; n < 4; ++n) {
        short8 b = *reinterpret_cast<const short8*>(
            Bf + (size_t)((((w << 2) | n) << 6) | l) * 8);
        #pragma unroll
        for (int m = 0; m < 4; ++m)
            acc[m][n] = __builtin_amdgcn_mfma_f32_16x16x32_bf16(a[m], b, acc[m][n],
                                                                0, 0, 0);
    }
}

// ---------------------------------------------------------------------------
// K12 fused: h = relu(clause@W1a + pe@C1 + C2[type] + beff) kept in LDS;
// xb = bf16( LN(h@W2 + b2 + clause) * g + b )
// ---------------------------------------------------------------------------
__global__ __launch_bounds__(256, 3) void k12_mfma(
    const float* __restrict__ clause, const float* __restrict__ ts,
    const int* __restrict__ types, const u16* __restrict__ wblob,
    const float* __restrict__ C2, const float* __restrict__ beff,
    const float* __restrict__ b2, const float* __restrict__ gW,
    const float* __restrict__ bW, u16* __restrict__ xb)
{
    __shared__ __align__(16) u16 Af[2048];    // 4KB; aliased as red later
    __shared__ __align__(16) u16 Bf[8192];    // 16KB
    __shared__ __align__(16) u16 hs[16384];   // 32KB swizzled h
    int tid = threadIdx.x, w = tid >> 6, l = tid & 63;
    int g = l >> 4, c0 = l & 15;
    int i0 = blockIdx.x * 64;
    int rowA = min(i0 + ((w << 4) | c0), N_NODES - 1);
    int kcol = g << 3;
    f32x4 acc[4][4] = {};

    // ---- GEMM1: K = 8*32 (clause) + 32 (pe)
    for (int t = 0; t < 9; ++t) {
        if (t < 8) {
            const float* p = clause + (size_t)rowA * H + t * 32 + kcol;
            float4 a = *reinterpret_cast<const float4*>(p);
            float4 b = *reinterpret_cast<const float4*>(p + 4);
            short8 v;
            v[0] = (short)f2bf(a.x); v[1] = (short)f2bf(a.y);
            v[2] = (short)f2bf(a.z); v[3] = (short)f2bf(a.w);
            v[4] = (short)f2bf(b.x); v[5] = (short)f2bf(b.y);
            v[6] = (short)f2bf(b.z); v[7] = (short)f2bf(b.w);
            *reinterpret_cast<short8*>(Af + (size_t)((w << 6) | l) * 8) = v;
        } else {
            float tsv = ts[rowA];
            short8 v;
            #pragma unroll
            for (int i = 0; i < 8; ++i) {
                int k = kcol + i;
                float fr = expf(-0.57564627324851f * (float)(k & 15));
                float ang = tsv * fr;
                float pv = (k < 16) ? sinf(ang) : cosf(ang);
                v[i] = (short)f2bf(pv);
            }
            *reinterpret_cast<short8*>(Af + (size_t)((w << 6) | l) * 8) = v;
        }
        #pragma unroll
        for (int it = 0; it < 4; ++it) {
            int c = (it << 8) + tid;
            gload16(wblob + (size_t)t * 8192 + (size_t)c * 8, Bf + (size_t)c * 8);
        }
        __syncthreads();
        mfma_step(Af, Bf, w, l, acc);
        __syncthreads();
    }

    // ---- h epilogue -> swizzled LDS (bf16)
    {
        float bev[4];
        #pragma unroll
        for (int n = 0; n < 4; ++n) bev[n] = beff[(w << 6) | (n << 4) | c0];
        #pragma unroll
        for (int m = 0; m < 4; ++m) {
            #pragma unroll
            for (int r = 0; r < 4; ++r) {
                int rl = (m << 4) + (g << 2) + r;
                int tp = types[min(i0 + rl, N_NODES - 1)];
                const float* c2r = C2 + (size_t)tp * H;
                #pragma unroll
                for (int n = 0; n < 4; ++n) {
                    int col = (w << 6) | (n << 4) | c0;
                    float val = fmaxf(acc[m][n][r] + bev[n] + c2r[col], 0.f);
                    hs[((rl << 8) + col) ^ ((rl & 7) << 3)] = f2bf(val);
                }
            }
        }
    }
    __syncthreads();

    // ---- GEMM2: K = 256, A from hs (swizzled reads, 2-way max)
    #pragma unroll
    for (int m = 0; m < 4; ++m)
        #pragma unroll
        for (int n = 0; n < 4; ++n)
            acc[m][n] = (f32x4){0.f, 0.f, 0.f, 0.f};

    for (int t = 0; t < 8; ++t) {
        #pragma unroll
        for (int it = 0; it < 4; ++it) {
            int c = (it << 8) + tid;
            gload16(wblob + (size_t)(9 + t) * 8192 + (size_t)c * 8,
                    Bf + (size_t)c * 8);
        }
        __syncthreads();
        short8 a[4];
        int colb = (t << 5) + kcol;
        #pragma unroll
        for (int m = 0; m < 4; ++m) {
            int rl2 = (m << 4) | c0;
            a[m] = *reinterpret_cast<const short8*>(
                &hs[((rl2 << 8) + colb) ^ ((c0 & 7) << 3)]);
        }
        #pragma unroll
        for (int n = 0; n < 4; ++n) {
            short8 b = *reinterpret_cast<const short8*>(
                Bf + (size_t)((((w << 2) | n) << 6) | l) * 8);
            #pragma unroll
            for (int m = 0; m < 4; ++m)
                acc[m][n] = __builtin_amdgcn_mfma_f32_16x16x32_bf16(a[m], b,
                                                                    acc[m][n], 0, 0, 0);
        }
        __syncthreads();
    }

    // ---- LN epilogue (residual = clause fp32, L2-hot)
    float2* red = reinterpret_cast<float2*>(Af);
    float bv[4], gv[4], bbv[4];
    #pragma unroll
    for (int n = 0; n < 4; ++n) {
        int col = (w << 6) | (n << 4) | c0;
        bv[n] = b2[col]; gv[n] = gW[col]; bbv[n] = bW[col];
    }
    #pragma unroll
    for (int m = 0; m < 4; ++m) {
        #pragma unroll
        for (int r = 0; r < 4; ++r) {
            int rl = (m << 4) + (g << 2) + r;
            int rowc = min(i0 + rl, N_NODES - 1);
            const float* cr = clause + (size_t)rowc * H;
            float s = 0.f, q = 0.f;
            #pragma unroll
            for (int n = 0; n < 4; ++n) {
                float pv = acc[m][n][r] + bv[n] + cr[(w << 6) | (n << 4) | c0];
                acc[m][n][r] = pv;
                s += pv; q += pv * pv;
            }
            #pragma unroll
            for (int o = 1; o < 16; o <<= 1) {
                s += __shfl_xor(s, o);
                q += __shfl_xor(q, o);
            }
            if (c0 == 0) red[(rl << 2) | w] = make_float2(s, q);
        }
    }
    __syncthreads();
    #pragma unroll
    for (int m = 0; m < 4; ++m) {
        #pragma unroll
        for (int r = 0; r < 4; ++r) {
            int rl = (m << 4) + (g << 2) + r;
            int row = i0 + rl;
            float2 t0 = red[(rl << 2) | 0], t1 = red[(rl << 2) | 1];
            float2 t2 = red[(rl << 2) | 2], t3 = red[(rl << 2) | 3];
            float S = t0.x + t1.x + t2.x + t3.x;
            float Q = t0.y + t1.y + t2.y + t3.y;
            float mu = S * (1.0f / 256.0f);
            float rstd = rsqrtf(Q * (1.0f / 256.0f) - mu * mu + 1e-5f);
            if (row < N_NODES) {
                #pragma unroll
                for (int n = 0; n < 4; ++n) {
                    int col = (w << 6) | (n << 4) | c0;
                    float val = (acc[m][n][r] - mu) * rstd * gv[n] + bbv[n];
                    xb[(size_t)row * H + col] = f2bf(val);
                }
            }
        }
    }
}

// ---------------------------------------------------------------------------
// K5: x' = LN(x + relu([x|agg]@Wl + bl))*g + b, x in bf16 (in-place safe:
// cross-node reads happened in gather). FINAL variant writes fp32 d_out.
// BK=64 (2 MFMA k-steps per chunk), all staging via global_load_lds.
// ---------------------------------------------------------------------------
template<bool FINAL>
__global__ __launch_bounds__(256, 4) void k5_mfma(
    const u16* __restrict__ xb, const u16* __restrict__ aggb,
    const u16* __restrict__ wblob, const float* __restrict__ bl,
    const float* __restrict__ gl, const float* __restrict__ bnl,
    u16* __restrict__ xbout, float* __restrict__ xout)
{
    __shared__ __align__(16) u16 Af[4096];    // 8KB (2 ksteps); aliased as red
    __shared__ __align__(16) u16 Bf[16384];   // 32KB (2 ksteps)
    int tid = threadIdx.x, w = tid >> 6, l = tid & 63;
    int g = l >> 4, c0 = l & 15;
    int i0 = blockIdx.x * 64;
    int rowA = min(i0 + ((w << 4) | c0), N_NODES - 1);
    int kcol = g << 3;
    f32x4 acc[4][4] = {};

    for (int t = 0; t < 8; ++t) {
        const u16* sb = (t < 4) ? xb : aggb;
        const u16* ap = sb + (size_t)rowA * H + ((t & 3) << 6) + kcol;
        gload16(ap,      Af + (size_t)((w << 6) | l) * 8);
        gload16(ap + 32, Af + 2048 + (size_t)((w << 6) | l) * 8);
        const u16* wk = wblob + (size_t)(t << 1) * 8192;
        #pragma unroll
        for (int it = 0; it < 4; ++it) {
            int c = (it << 8) + tid;
            gload16(wk + (size_t)c * 8,        Bf + (size_t)c * 8);
            gload16(wk + 8192 + (size_t)c * 8, Bf + 8192 + (size_t)c * 8);
        }
        __syncthreads();
        mfma_step(Af, Bf, w, l, acc);
        mfma_step(Af + 2048, Bf + 8192, w, l, acc);
        __syncthreads();
    }

    float2* red = reinterpret_cast<float2*>(Af);
    float bv[4], gv[4], bbv[4];
    #pragma unroll
    for (int n = 0; n < 4; ++n) {
        int col = (w << 6) | (n << 4) | c0;
        bv[n] = bl[col]; gv[n] = gl[col]; bbv[n] = bnl[col];
    }
    #pragma unroll
    for (int m = 0; m < 4; ++m) {
        #pragma unroll
        for (int r = 0; r < 4; ++r) {
            int rl = (m << 4) + (g << 2) + r;
            int rowc = min(i0 + rl, N_NODES - 1);
            const u16* xr = xb + (size_t)rowc * H;
            float s = 0.f, q = 0.f;
            #pragma unroll
            for (int n = 0; n < 4; ++n) {
                int col = (w << 6) | (n << 4) | c0;
                float pv = bf2f(xr[col]) + fmaxf(acc[m][n][r] + bv[n], 0.f);
                acc[m][n][r] = pv;
                s += pv; q += pv * pv;
            }
            #pragma unroll
            for (int o = 1; o < 16; o <<= 1) {
                s += __shfl_xor(s, o);
                q += __shfl_xor(q, o);
            }
            if (c0 == 0) red[(rl << 2) | w] = make_float2(s, q);
        }
    }
    __syncthreads();
    #pragma unroll
    for (int m = 0; m < 4; ++m) {
        #pragma unroll
        for (int r = 0; r < 4; ++r) {
            int rl = (m << 4) + (g << 2) + r;
            int row = i0 + rl;
            float2 t0 = red[(rl << 2) | 0], t1 = red[(rl << 2) | 1];
            float2 t2 = red[(rl << 2) | 2], t3 = red[(rl << 2) | 3];
            float S = t0.x + t1.x + t2.x + t3.x;
            float Q = t0.y + t1.y + t2.y + t3.y;
            float mu = S * (1.0f / 256.0f);
            float rstd = rsqrtf(Q * (1.0f / 256.0f) - mu * mu + 1e-5f);
            if (row < N_NODES) {
                #pragma unroll
                for (int n = 0; n < 4; ++n) {
                    int col = (w << 6) | (n << 4) | c0;
                    float val = (acc[m][n][r] - mu) * rstd * gv[n] + bbv[n];
                    if (FINAL) xout[(size_t)row * H + col] = val;
                    else       xbout[(size_t)row * H + col] = f2bf(val);
                }
            }
        }
    }
}

// ---------------------------------------------------------------------------
extern "C" void kernel_launch(void* const* d_in, const int* in_sizes, int n_in,
                              void* d_out, int out_size, void* d_ws, size_t ws_size,
                              hipStream_t stream)
{
    const float* clause  = (const float*)d_in[0];
    const float* ts      = (const float*)d_in[1];
    const int*   types   = (const int*)  d_in[2];
    const int*   edges   = (const int*)  d_in[3];
    const float* emb     = (const float*)d_in[4];
    const float* temp_W  = (const float*)d_in[5];
    const float* temp_b  = (const float*)d_in[6];
    const float* fus_W1  = (const float*)d_in[7];
    const float* fus_b1  = (const float*)d_in[8];
    const float* fus_W2  = (const float*)d_in[9];
    const float* fus_b2  = (const float*)d_in[10];
    const float* in_g    = (const float*)d_in[11];
    const float* in_b    = (const float*)d_in[12];
    const float* deriv_W = (const float*)d_in[13];
    const float* deriv_b = (const float*)d_in[14];
    const float* dn_g    = (const float*)d_in[15];
    const float* dn_b    = (const float*)d_in[16];

    char* p = (char*)d_ws;
    float* C1   = (float*)p;            p += 32 * H * 4;
    float* C2   = (float*)p;            p += NTYPES * H * 4;
    float* beff = (float*)p;            p += H * 4;
    int* cnt    = (int*)p;              p += N_NODES * 4;
    int* off    = (int*)p;              p += N_NODES * 4;
    int* cursor = (int*)p;              p += N_NODES * 4;
    int* bsum   = (int*)p;              p += 128 * 4;
    int* bbase  = (int*)p;              p += 128 * 4;
    int* csr    = (int*)p;              p += N_EDGES * 4;
    u16* wblob  = (u16*)p;              p += 49 * 8192 * 2;
    u16* xb16   = (u16*)p;              p += (size_t)N_NODES * H * 2;
    u16* aggb16 = (u16*)p;              p += (size_t)N_NODES * H * 2;
    float* x    = (float*)d_out;

    const int* src = edges;
    const int* dst = edges + N_EDGES;

    prep_small<<<32 + NTYPES + 1, 256, 0, stream>>>(temp_W, temp_b, emb, fus_W1,
                                                    fus_b1, C1, C2, beff);
    prep_frag<<<49, 256, 0, stream>>>(fus_W1, C1, fus_W2, deriv_W, wblob);

    hipMemsetAsync(cnt, 0, N_NODES * sizeof(int), stream);
    count_kernel<<<(N_EDGES + 255) / 256, 256, 0, stream>>>(dst, cnt);
    scan1_kernel<<<SCAN_G, 1024, 0, stream>>>(cnt, off, bsum);
    scan2_kernel<<<1, 64, 0, stream>>>(bsum, bbase);
    scan3_kernel<<<SCAN_G, 1024, 0, stream>>>(off, bbase, cnt, cursor);
    fill_kernel<<<(N_EDGES + 255) / 256, 256, 0, stream>>>(src, dst, cursor, csr);

    k12_mfma<<<GRID_G, 256, 0, stream>>>(clause, ts, types, wblob, C2, beff,
                                         fus_b2, in_g, in_b, xb16);

    // layer 0 (bf16 in-place)
    gather_kernel<<<N_NODES / 4, 256, 0, stream>>>(xb16, csr, off, cnt, aggb16);
    k5_mfma<false><<<GRID_G, 256, 0, stream>>>(
        xb16, aggb16, wblob + (size_t)17 * 8192,
        deriv_b, dn_g, dn_b, xb16, nullptr);
    // layer 1 (writes fp32 d_out)
    gather_kernel<<<N_NODES / 4, 256, 0, stream>>>(xb16, csr, off, cnt, aggb16);
    k5_mfma<true><<<GRID_G, 256, 0, stream>>>(
        xb16, aggb16, wblob + (size_t)33 * 8192,
        deriv_b + H, dn_g + H, dn_b + H, nullptr, x);
}

// Round 5
// 527.781 us; speedup vs baseline: 1.0697x; 1.0697x over previous
//
#include <hip/hip_runtime.h>
#include <hip/hip_bf16.h>
#include <math.h>

#define N_NODES 100000
#define N_EDGES 800000
#define H 256
#define NTYPES 22
#define SCAN_G 98                        // ceil(100000/1024)
#define GRID5 ((N_NODES + 127) / 128)    // 782 blocks of BM=128

typedef __attribute__((ext_vector_type(8))) short short8;
typedef __attribute__((ext_vector_type(4))) float f32x4;
typedef unsigned short u16;

__device__ __forceinline__ u16 f2bf(float f) {
    unsigned u = __float_as_uint(f);
    u += 0x7FFF + ((u >> 16) & 1);      // RNE
    return (u16)(u >> 16);
}
__device__ __forceinline__ float bf2f(u16 u) {
    return __uint_as_float(((unsigned)u) << 16);
}
// sigma^-1: memcol -> logical col (also used for K-row permutation of weights)
__device__ __forceinline__ int pi2(int k) {
    return (k & 192) | ((k & 3) << 4) | ((k >> 2) & 15);
}

// async global->LDS, 16B/lane; HW uses lane0's LDS ptr as wave base + lane*16
__device__ __forceinline__ void gload16(const void* g, void* l) {
    __builtin_amdgcn_global_load_lds(
        (const __attribute__((address_space(1))) unsigned int*)g,
        (__attribute__((address_space(3))) unsigned int*)l, 16, 0, 0);
}

// ---------------------------------------------------------------------------
// conv: clause fp32 -> bf16 (logical col order), fully coalesced
// ---------------------------------------------------------------------------
__global__ __launch_bounds__(256) void conv_bf16(
    const float* __restrict__ src, u16* __restrict__ dst)
{
    size_t i = (size_t)blockIdx.x * 256 + threadIdx.x;   // one per 8 elems
    const float4 a = ((const float4*)src)[i * 2];
    const float4 b = ((const float4*)src)[i * 2 + 1];
    short8 v;
    v[0] = (short)f2bf(a.x); v[1] = (short)f2bf(a.y);
    v[2] = (short)f2bf(a.z); v[3] = (short)f2bf(a.w);
    v[4] = (short)f2bf(b.x); v[5] = (short)f2bf(b.y);
    v[6] = (short)f2bf(b.z); v[7] = (short)f2bf(b.w);
    ((short8*)dst)[i] = v;
}

// ---------------------------------------------------------------------------
// prep_small: C1 = temp_W @ W1b (32x256), C2 = emb @ W1c (22x256),
// beff = fus_b1 + temp_b @ W1b (256)   (all logical order, fp32)
// ---------------------------------------------------------------------------
__global__ __launch_bounds__(256) void prep_small(
    const float* __restrict__ temp_W, const float* __restrict__ temp_b,
    const float* __restrict__ emb, const float* __restrict__ fus_W1,
    const float* __restrict__ fus_b1,
    float* __restrict__ C1, float* __restrict__ C2, float* __restrict__ beff)
{
    int b = blockIdx.x;
    int j = threadIdx.x;
    if (b < 32) {
        float acc = 0.f;
        #pragma unroll 8
        for (int m = 0; m < H; ++m)
            acc += temp_W[b * H + m] * fus_W1[(size_t)(H + m) * H + j];
        C1[b * H + j] = acc;
    } else if (b < 32 + NTYPES) {
        int e = b - 32;
        float acc = 0.f;
        #pragma unroll 8
        for (int m = 0; m < H; ++m)
            acc += emb[e * H + m] * fus_W1[(size_t)(2 * H + m) * H + j];
        C2[e * H + j] = acc;
    } else {
        float acc = fus_b1[j];
        #pragma unroll 8
        for (int m = 0; m < H; ++m)
            acc += temp_b[m] * fus_W1[(size_t)(H + m) * H + j];
        beff[j] = acc;
    }
}

// ---------------------------------------------------------------------------
// prep_frag: pack weights into MFMA B-fragment order, bf16.
// Blob: kstep s (49) x chunk c (1024) x 8 bf16; c = nt*64+l ->
// W col = nt*16+(l&15), k_in_step = 8*(l>>4)+i.
// K-rows: s0..7 fus_W1 clause part (logical: clause_bf is logical);
// s8 C1 (logical); s9..16 fus_W2 (pi2: h is sigma-ordered);
// s17..32 deriv_W[0], s33..48 deriv_W[1] (pi2 within each 256-half).
// ---------------------------------------------------------------------------
__global__ __launch_bounds__(256) void prep_frag(
    const float* __restrict__ fus_W1, const float* __restrict__ C1,
    const float* __restrict__ fus_W2, const float* __restrict__ deriv_W,
    u16* __restrict__ wblob)
{
    int s = blockIdx.x;
    #pragma unroll
    for (int it = 0; it < 4; ++it) {
        int c = it * 256 + threadIdx.x;
        int l = c & 63, nt = c >> 6;
        int ncol = (nt << 4) | (l & 15);
        int kin = (l >> 4) << 3;
        short8 v;
        #pragma unroll
        for (int i = 0; i < 8; ++i) {
            const float* srcp;
            if (s < 8) {
                srcp = fus_W1 + (size_t)(s * 32 + kin + i) * H;
            } else if (s == 8) {
                srcp = C1 + (size_t)(kin + i) * H;
            } else if (s < 17) {
                int k = (s - 9) * 32 + kin + i;
                srcp = fus_W2 + (size_t)pi2(k) * H;
            } else if (s < 33) {
                int k = (s - 17) * 32 + kin + i;
                srcp = deriv_W + (size_t)((k >> 8) * 256 + pi2(k & 255)) * H;
            } else {
                int k = (s - 33) * 32 + kin + i;
                srcp = deriv_W + (size_t)(512 + (k >> 8) * 256 + pi2(k & 255)) * H;
            }
            v[i] = (short)f2bf(srcp[ncol]);
        }
        *reinterpret_cast<short8*>(wblob + (size_t)s * 8192 + (size_t)c * 8) = v;
    }
}

// ---------------------------------------------------------------------------
// CSR build
// ---------------------------------------------------------------------------
__global__ void count_kernel(const int* __restrict__ dst, int* __restrict__ cnt)
{
    int e = blockIdx.x * blockDim.x + threadIdx.x;
    if (e < N_EDGES) atomicAdd(&cnt[dst[e]], 1);
}

__global__ __launch_bounds__(1024) void scan1_kernel(
    const int* __restrict__ cnt, int* __restrict__ off, int* __restrict__ bsum)
{
    __shared__ int s[1024];
    int i = blockIdx.x * 1024 + threadIdx.x;
    int v = (i < N_NODES) ? cnt[i] : 0;
    s[threadIdx.x] = v;
    __syncthreads();
    #pragma unroll
    for (int o = 1; o < 1024; o <<= 1) {
        int t = (threadIdx.x >= o) ? s[threadIdx.x - o] : 0;
        __syncthreads();
        s[threadIdx.x] += t;
        __syncthreads();
    }
    if (i < N_NODES) off[i] = s[threadIdx.x];
    if (threadIdx.x == 1023) bsum[blockIdx.x] = s[1023];
}

__global__ void scan2_kernel(const int* __restrict__ bsum, int* __restrict__ bbase)
{
    if (threadIdx.x == 0) {
        int acc = 0;
        for (int b = 0; b < SCAN_G; ++b) { bbase[b] = acc; acc += bsum[b]; }
    }
}

__global__ __launch_bounds__(1024) void scan3_kernel(
    int* __restrict__ off, const int* __restrict__ bbase,
    const int* __restrict__ cnt, int* __restrict__ cursor)
{
    int i = blockIdx.x * 1024 + threadIdx.x;
    if (i < N_NODES) {
        int incl = off[i] + bbase[blockIdx.x];
        off[i] = incl;
        cursor[i] = incl - cnt[i];
    }
}

__global__ void fill_kernel(const int* __restrict__ src, const int* __restrict__ dst,
                            int* __restrict__ cursor, int* __restrict__ csr)
{
    int e = blockIdx.x * blockDim.x + threadIdx.x;
    if (e < N_EDGES) {
        int pos = atomicAdd(&cursor[dst[e]], 1);
        csr[pos] = src[e];
    }
}

// ---------------------------------------------------------------------------
// gather: one wave per node; mean of parent rows (bf16, sigma-invariant)
// ---------------------------------------------------------------------------
__global__ __launch_bounds__(256) void gather_kernel(
    const u16* __restrict__ xb, const int* __restrict__ csr,
    const int* __restrict__ off, const int* __restrict__ cnt,
    u16* __restrict__ agg)
{
    int node = blockIdx.x * 4 + (threadIdx.x >> 6);
    int l = threadIdx.x & 63;
    int deg = cnt[node];
    int start = off[node] - deg;
    float a0 = 0.f, a1 = 0.f, a2 = 0.f, a3 = 0.f;
    float b0 = 0.f, b1 = 0.f, b2 = 0.f, b3 = 0.f;
    int j = 0;
    for (; j + 1 < deg; j += 2) {
        int s0 = csr[start + j], s1 = csr[start + j + 1];
        ushort4 v0 = *reinterpret_cast<const ushort4*>(xb + (size_t)s0 * H + l * 4);
        ushort4 v1 = *reinterpret_cast<const ushort4*>(xb + (size_t)s1 * H + l * 4);
        a0 += bf2f(v0.x); a1 += bf2f(v0.y); a2 += bf2f(v0.z); a3 += bf2f(v0.w);
        b0 += bf2f(v1.x); b1 += bf2f(v1.y); b2 += bf2f(v1.z); b3 += bf2f(v1.w);
    }
    if (j < deg) {
        int s0 = csr[start + j];
        ushort4 v0 = *reinterpret_cast<const ushort4*>(xb + (size_t)s0 * H + l * 4);
        a0 += bf2f(v0.x); a1 += bf2f(v0.y); a2 += bf2f(v0.z); a3 += bf2f(v0.w);
    }
    float sc = 1.0f / fmaxf((float)deg, 1.0f);
    ushort4 o;
    o.x = f2bf((a0 + b0) * sc); o.y = f2bf((a1 + b1) * sc);
    o.z = f2bf((a2 + b2) * sc); o.w = f2bf((a3 + b3) * sc);
    *reinterpret_cast<ushort4*>(agg + (size_t)node * H + l * 4) = o;
}

// ---------------------------------------------------------------------------
// 8-wave GEMM helpers: BM=128, BN=256, BK=32; wave (wm=w>>2, wn=w&3)
// owns out rows [wm*64+m*16) x ntiles wn*4+n.
// ---------------------------------------------------------------------------
__device__ __forceinline__ void stageA8(u16* Af, const u16* __restrict__ src,
                                        int i0, int kbase, int tid)
{
    int rt = tid >> 6, l = tid & 63;
    int row = min(i0 + rt * 16 + (l & 15), N_NODES - 1);
    gload16(src + (size_t)row * H + kbase + ((l >> 4) << 3), Af + (tid << 3));
}

__device__ __forceinline__ void stageB8(u16* Bf, const u16* __restrict__ wk, int tid)
{
    gload16(wk + ((size_t)tid << 3),         Bf + (tid << 3));
    gload16(wk + ((size_t)(tid + 512) << 3), Bf + ((tid + 512) << 3));
}

__device__ __forceinline__ void mfma_step8(const u16* Af, const u16* Bf,
                                           int wm, int wn, int l, f32x4 acc[4][4])
{
    short8 a[4], b[4];
    #pragma unroll
    for (int m = 0; m < 4; ++m)
        a[m] = *reinterpret_cast<const short8*>(Af + ((((wm << 2) | m) << 6 | l) << 3));
    #pragma unroll
    for (int n = 0; n < 4; ++n)
        b[n] = *reinterpret_cast<const short8*>(Bf + ((((wn << 2) | n) << 6 | l) << 3));
    #pragma unroll
    for (int n = 0; n < 4; ++n)
        #pragma unroll
        for (int m = 0; m < 4; ++m)
            acc[m][n] = __builtin_amdgcn_mfma_f32_16x16x32_bf16(a[m], b[n],
                                                                acc[m][n], 0, 0, 0);
}

// ---------------------------------------------------------------------------
// K1: h = relu(clause@W1a + pe@C1 + C2[type] + beff); h sigma-ordered bf16
// ---------------------------------------------------------------------------
__global__ __launch_bounds__(512, 4) void k1_mfma(
    const u16* __restrict__ cb, const float* __restrict__ ts,
    const int* __restrict__ types, const u16* __restrict__ wblob,
    const float* __restrict__ C2, const float* __restrict__ beff,
    u16* __restrict__ hb)
{
    __shared__ __align__(16) u16 Af[4096];
    __shared__ __align__(16) u16 Bf[8192];
    int tid = threadIdx.x, w = tid >> 6, l = tid & 63;
    int wm = w >> 2, wn = w & 3, g = l >> 4, c0 = l & 15;
    int i0 = blockIdx.x * 128;
    f32x4 acc[4][4] = {};

    for (int t = 0; t < 9; ++t) {
        if (t < 8) {
            stageA8(Af, cb, i0, t * 32, tid);
        } else {
            int rt = tid >> 6;
            int row = min(i0 + rt * 16 + c0, N_NODES - 1);
            float tsv = ts[row];
            short8 v;
            #pragma unroll
            for (int i = 0; i < 8; ++i) {
                int k = (g << 3) + i;
                float fr = expf(-0.57564627324851f * (float)(k & 15));
                float ang = tsv * fr;
                float pv = (k < 16) ? sinf(ang) : cosf(ang);
                v[i] = (short)f2bf(pv);
            }
            *reinterpret_cast<short8*>(Af + (tid << 3)) = v;
        }
        stageB8(Bf, wblob + (size_t)t * 8192, tid);
        __syncthreads();
        mfma_step8(Af, Bf, wm, wn, l, acc);
        __syncthreads();
    }

    float bev[4];
    #pragma unroll
    for (int n = 0; n < 4; ++n) bev[n] = beff[(((wn << 2) | n) << 4) | c0];
    #pragma unroll
    for (int m = 0; m < 4; ++m) {
        #pragma unroll
        for (int r = 0; r < 4; ++r) {
            int rl = (((wm << 2) | m) << 4) + (g << 2) + r;
            int row = i0 + rl;
            bool ok = row < N_NODES;
            int tp = types[ok ? row : 0];
            const float* c2r = C2 + (size_t)tp * H;
            ushort4 o;
            float v0 = fmaxf(acc[m][0][r] + bev[0] + c2r[((wn << 2) << 4) | c0], 0.f);
            float v1 = fmaxf(acc[m][1][r] + bev[1] + c2r[(((wn << 2) | 1) << 4) | c0], 0.f);
            float v2 = fmaxf(acc[m][2][r] + bev[2] + c2r[(((wn << 2) | 2) << 4) | c0], 0.f);
            float v3 = fmaxf(acc[m][3][r] + bev[3] + c2r[(((wn << 2) | 3) << 4) | c0], 0.f);
            o.x = f2bf(v0); o.y = f2bf(v1); o.z = f2bf(v2); o.w = f2bf(v3);
            if (ok)
                *reinterpret_cast<ushort4*>(hb + (size_t)row * H + (wn << 6) + (c0 << 2)) = o;
        }
    }
}

// ---------------------------------------------------------------------------
// K2: xb = bf16(LN(h@W2 + b2 + clause) * g + b); in-place hb==xb allowed
// ---------------------------------------------------------------------------
__global__ __launch_bounds__(512, 4) void k2_mfma(
    const u16* __restrict__ hb, const u16* __restrict__ cb,
    const u16* __restrict__ wblob, const float* __restrict__ b2,
    const float* __restrict__ gW, const float* __restrict__ bW,
    u16* __restrict__ xb)
{
    __shared__ __align__(16) u16 Af[4096];
    __shared__ __align__(16) u16 Bf[8192];
    int tid = threadIdx.x, w = tid >> 6, l = tid & 63;
    int wm = w >> 2, wn = w & 3, g = l >> 4, c0 = l & 15;
    int i0 = blockIdx.x * 128;
    f32x4 acc[4][4] = {};

    for (int t = 0; t < 8; ++t) {
        stageA8(Af, hb, i0, t * 32, tid);
        stageB8(Bf, wblob + (size_t)t * 8192, tid);
        __syncthreads();
        mfma_step8(Af, Bf, wm, wn, l, acc);
        __syncthreads();
    }

    float bv[4], gv[4], bbv[4];
    int lc[4];
    #pragma unroll
    for (int n = 0; n < 4; ++n) {
        lc[n] = (((wn << 2) | n) << 4) | c0;
        bv[n] = b2[lc[n]]; gv[n] = gW[lc[n]]; bbv[n] = bW[lc[n]];
    }
    float2* red = reinterpret_cast<float2*>(Af);
    #pragma unroll
    for (int m = 0; m < 4; ++m) {
        #pragma unroll
        for (int r = 0; r < 4; ++r) {
            int rl = (((wm << 2) | m) << 4) + (g << 2) + r;
            int rowc = min(i0 + rl, N_NODES - 1);
            const u16* cr = cb + (size_t)rowc * H;   // logical order
            float s = 0.f, q = 0.f;
            #pragma unroll
            for (int n = 0; n < 4; ++n) {
                float pv = acc[m][n][r] + bv[n] + bf2f(cr[lc[n]]);
                acc[m][n][r] = pv;
                s += pv; q += pv * pv;
            }
            #pragma unroll
            for (int o = 1; o < 16; o <<= 1) {
                s += __shfl_xor(s, o);
                q += __shfl_xor(q, o);
            }
            if (c0 == 0) red[(rl << 2) | wn] = make_float2(s, q);
        }
    }
    __syncthreads();
    #pragma unroll
    for (int m = 0; m < 4; ++m) {
        #pragma unroll
        for (int r = 0; r < 4; ++r) {
            int rl = (((wm << 2) | m) << 4) + (g << 2) + r;
            int row = i0 + rl;
            float2 t0 = red[(rl << 2) | 0], t1 = red[(rl << 2) | 1];
            float2 t2 = red[(rl << 2) | 2], t3 = red[(rl << 2) | 3];
            float S = t0.x + t1.x + t2.x + t3.x;
            float Q = t0.y + t1.y + t2.y + t3.y;
            float mu = S * (1.0f / 256.0f);
            float rstd = rsqrtf(Q * (1.0f / 256.0f) - mu * mu + 1e-5f);
            if (row < N_NODES) {
                ushort4 o;
                o.x = f2bf((acc[m][0][r] - mu) * rstd * gv[0] + bbv[0]);
                o.y = f2bf((acc[m][1][r] - mu) * rstd * gv[1] + bbv[1]);
                o.z = f2bf((acc[m][2][r] - mu) * rstd * gv[2] + bbv[2]);
                o.w = f2bf((acc[m][3][r] - mu) * rstd * gv[3] + bbv[3]);
                *reinterpret_cast<ushort4*>(xb + (size_t)row * H + (wn << 6) + (c0 << 2)) = o;
            }
        }
    }
}

// ---------------------------------------------------------------------------
// K5: x' = LN(x + relu([x|agg]@Wl + bl))*g + b; in-place on xb.
// FINAL writes fp32 d_out in logical column order.
// ---------------------------------------------------------------------------
template<bool FINAL>
__global__ __launch_bounds__(512, 4) void k5_mfma(
    const u16* __restrict__ xb, const u16* __restrict__ aggb,
    const u16* __restrict__ wblob, const float* __restrict__ bl,
    const float* __restrict__ gl, const float* __restrict__ bnl,
    u16* __restrict__ xbout, float* __restrict__ xout)
{
    __shared__ __align__(16) u16 Af[4096];
    __shared__ __align__(16) u16 Bf[8192];
    int tid = threadIdx.x, w = tid >> 6, l = tid & 63;
    int wm = w >> 2, wn = w & 3, g = l >> 4, c0 = l & 15;
    int i0 = blockIdx.x * 128;
    f32x4 acc[4][4] = {};

    for (int t = 0; t < 16; ++t) {
        stageA8(Af, (t < 8) ? xb : aggb, i0, (t & 7) * 32, tid);
        stageB8(Bf, wblob + (size_t)t * 8192, tid);
        __syncthreads();
        mfma_step8(Af, Bf, wm, wn, l, acc);
        __syncthreads();
    }

    float bv[4], gv[4], bbv[4];
    int lc[4];
    #pragma unroll
    for (int n = 0; n < 4; ++n) {
        lc[n] = (((wn << 2) | n) << 4) | c0;
        bv[n] = bl[lc[n]]; gv[n] = gl[lc[n]]; bbv[n] = bnl[lc[n]];
    }
    float2* red = reinterpret_cast<float2*>(Af);
    #pragma unroll
    for (int m = 0; m < 4; ++m) {
        #pragma unroll
        for (int r = 0; r < 4; ++r) {
            int rl = (((wm << 2) | m) << 4) + (g << 2) + r;
            int rowc = min(i0 + rl, N_NODES - 1);
            ushort4 xr = *reinterpret_cast<const ushort4*>(
                xb + (size_t)rowc * H + (wn << 6) + (c0 << 2));
            float s = 0.f, q = 0.f;
            float p0 = bf2f(xr.x) + fmaxf(acc[m][0][r] + bv[0], 0.f);
            float p1 = bf2f(xr.y) + fmaxf(acc[m][1][r] + bv[1], 0.f);
            float p2 = bf2f(xr.z) + fmaxf(acc[m][2][r] + bv[2], 0.f);
            float p3 = bf2f(xr.w) + fmaxf(acc[m][3][r] + bv[3], 0.f);
            acc[m][0][r] = p0; acc[m][1][r] = p1;
            acc[m][2][r] = p2; acc[m][3][r] = p3;
            s = p0 + p1 + p2 + p3;
            q = p0 * p0 + p1 * p1 + p2 * p2 + p3 * p3;
            #pragma unroll
            for (int o = 1; o < 16; o <<= 1) {
                s += __shfl_xor(s, o);
                q += __shfl_xor(q, o);
            }
            if (c0 == 0) red[(rl << 2) | wn] = make_float2(s, q);
        }
    }
    __syncthreads();
    #pragma unroll
    for (int m = 0; m < 4; ++m) {
        #pragma unroll
        for (int r = 0; r < 4; ++r) {
            int rl = (((wm << 2) | m) << 4) + (g << 2) + r;
            int row = i0 + rl;
            float2 t0 = red[(rl << 2) | 0], t1 = red[(rl << 2) | 1];
            float2 t2 = red[(rl << 2) | 2], t3 = red[(rl << 2) | 3];
            float S = t0.x + t1.x + t2.x + t3.x;
            float Q = t0.y + t1.y + t2.y + t3.y;
            float mu = S * (1.0f / 256.0f);
            float rstd = rsqrtf(Q * (1.0f / 256.0f) - mu * mu + 1e-5f);
            if (row < N_NODES) {
                if (FINAL) {
                    #pragma unroll
                    for (int n = 0; n < 4; ++n)
                        xout[(size_t)row * H + lc[n]] =
                            (acc[m][n][r] - mu) * rstd * gv[n] + bbv[n];
                } else {
                    ushort4 o;
                    o.x = f2bf((acc[m][0][r] - mu) * rstd * gv[0] + bbv[0]);
                    o.y = f2bf((acc[m][1][r] - mu) * rstd * gv[1] + bbv[1]);
                    o.z = f2bf((acc[m][2][r] - mu) * rstd * gv[2] + bbv[2]);
                    o.w = f2bf((acc[m][3][r] - mu) * rstd * gv[3] + bbv[3]);
                    *reinterpret_cast<ushort4*>(
                        xbout + (size_t)row * H + (wn << 6) + (c0 << 2)) = o;
                }
            }
        }
    }
}

// ---------------------------------------------------------------------------
extern "C" void kernel_launch(void* const* d_in, const int* in_sizes, int n_in,
                              void* d_out, int out_size, void* d_ws, size_t ws_size,
                              hipStream_t stream)
{
    const float* clause  = (const float*)d_in[0];
    const float* ts      = (const float*)d_in[1];
    const int*   types   = (const int*)  d_in[2];
    const int*   edges   = (const int*)  d_in[3];
    const float* emb     = (const float*)d_in[4];
    const float* temp_W  = (const float*)d_in[5];
    const float* temp_b  = (const float*)d_in[6];
    const float* fus_W1  = (const float*)d_in[7];
    const float* fus_b1  = (const float*)d_in[8];
    const float* fus_W2  = (const float*)d_in[9];
    const float* fus_b2  = (const float*)d_in[10];
    const float* in_g    = (const float*)d_in[11];
    const float* in_b    = (const float*)d_in[12];
    const float* deriv_W = (const float*)d_in[13];
    const float* deriv_b = (const float*)d_in[14];
    const float* dn_g    = (const float*)d_in[15];
    const float* dn_b    = (const float*)d_in[16];

    char* p = (char*)d_ws;
    float* C1   = (float*)p;            p += 32 * H * 4;
    float* C2   = (float*)p;            p += NTYPES * H * 4;
    float* beff = (float*)p;            p += H * 4;
    int* cnt    = (int*)p;              p += N_NODES * 4;
    int* off    = (int*)p;              p += N_NODES * 4;
    int* cursor = (int*)p;              p += N_NODES * 4;
    int* bsum   = (int*)p;              p += 128 * 4;
    int* bbase  = (int*)p;              p += 128 * 4;
    int* csr    = (int*)p;              p += N_EDGES * 4;
    u16* wblob  = (u16*)p;              p += 49 * 8192 * 2;
    u16* B1     = (u16*)p;              p += (size_t)N_NODES * H * 2;  // clause_bf / agg
    u16* B2     = (u16*)p;              p += (size_t)N_NODES * H * 2;  // h / xb
    float* x    = (float*)d_out;

    const int* src = edges;
    const int* dst = edges + N_EDGES;

    conv_bf16<<<(N_NODES * H / 8 + 255) / 256, 256, 0, stream>>>(clause, B1);
    prep_small<<<32 + NTYPES + 1, 256, 0, stream>>>(temp_W, temp_b, emb, fus_W1,
                                                    fus_b1, C1, C2, beff);
    prep_frag<<<49, 256, 0, stream>>>(fus_W1, C1, fus_W2, deriv_W, wblob);

    hipMemsetAsync(cnt, 0, N_NODES * sizeof(int), stream);
    count_kernel<<<(N_EDGES + 255) / 256, 256, 0, stream>>>(dst, cnt);
    scan1_kernel<<<SCAN_G, 1024, 0, stream>>>(cnt, off, bsum);
    scan2_kernel<<<1, 64, 0, stream>>>(bsum, bbase);
    scan3_kernel<<<SCAN_G, 1024, 0, stream>>>(off, bbase, cnt, cursor);
    fill_kernel<<<(N_EDGES + 255) / 256, 256, 0, stream>>>(src, dst, cursor, csr);

    k1_mfma<<<GRID5, 512, 0, stream>>>(B1, ts, types, wblob, C2, beff, B2);
    k2_mfma<<<GRID5, 512, 0, stream>>>(B2, B1, wblob + (size_t)9 * 8192,
                                       fus_b2, in_g, in_b, B2);

    // layer 0 (bf16 in-place on B2; B1 becomes agg)
    gather_kernel<<<N_NODES / 4, 256, 0, stream>>>(B2, csr, off, cnt, B1);
    k5_mfma<false><<<GRID5, 512, 0, stream>>>(
        B2, B1, wblob + (size_t)17 * 8192, deriv_b, dn_g, dn_b, B2, nullptr);
    // layer 1 (writes fp32 d_out, logical order)
    gather_kernel<<<N_NODES / 4, 256, 0, stream>>>(B2, csr, off, cnt, B1);
    k5_mfma<true><<<GRID5, 512, 0, stream>>>(
        B2, B1, wblob + (size_t)33 * 8192, deriv_b + H, dn_g + H, dn_b + H,
        nullptr, x);
}